// Round 1
// 269.245 us; speedup vs baseline: 1.0891x; 1.0891x over previous
//
#include <hip/hip_runtime.h>
#include <hip/hip_bf16.h>

#define N_TOK 8192
#define DM 1024
#define KD 64
#define ODIM 1024
#define LOG2E 1.4426950408889634f

typedef unsigned short ushort_t;
typedef __attribute__((ext_vector_type(8))) short short8;
typedef __attribute__((ext_vector_type(4))) float f32x4;

#define MFMA16(a, b, c) __builtin_amdgcn_mfma_f32_16x16x32_bf16((a), (b), (c), 0, 0, 0)

__device__ __forceinline__ float ex2(float x) {
#if __has_builtin(__builtin_amdgcn_exp2f)
    return __builtin_amdgcn_exp2f(x);
#else
    return exp2f(x);
#endif
}
// RNE float->bf16 (finite inputs)
__device__ __forceinline__ ushort_t rne(float x) {
    unsigned u = __float_as_uint(x);
    u += 0x7fffu + ((u >> 16) & 1u);
    return (ushort_t)(u >> 16);
}
__device__ __forceinline__ float ubf(ushort_t h) {
    return __uint_as_float(((unsigned)h) << 16);
}
__device__ __forceinline__ void split2(float x, ushort_t& hi, ushort_t& lo) {
    hi = rne(x);
    lo = rne(x - ubf(hi));
}
__device__ __forceinline__ unsigned bfpack(float a, float b) {
    unsigned ua = __float_as_uint(a); ua += 0x7fffu + ((ua >> 16) & 1u);
    unsigned ub = __float_as_uint(b); ub += 0x7fffu + ((ub >> 16) & 1u);
    return (ua >> 16) | (ub & 0xffff0000u);
}
// async global->LDS, 16B per lane; lds dst must be wave-uniform base (+lane*16 implicit)
__device__ __forceinline__ void gld_lds16(const void* g, void* l) {
    __builtin_amdgcn_global_load_lds(
        (const __attribute__((address_space(1))) unsigned int*)g,
        (__attribute__((address_space(3))) unsigned int*)l, 16, 0, 0);
}

// ---------------- Kernel 0: weight transpose + hi/lo split ----------------
__global__ __launch_bounds__(256) void prep_kernel(
    const float* __restrict__ wq, const float* __restrict__ wo,
    ushort_t* __restrict__ wT_hi, ushort_t* __restrict__ wT_lo,
    ushort_t* __restrict__ woT_hi, ushort_t* __restrict__ woT_lo)
{
    const int idx = blockIdx.x * 256 + threadIdx.x;   // 262144 = 192K + 64K
    if (idx < 192 * 1024) {
        const int c = idx >> 10, k = idx & 1023;
        ushort_t h, l; split2(wq[k * 192 + c], h, l);
        wT_hi[idx] = h; wT_lo[idx] = l;
    } else {
        const int j = idx - 192 * 1024;
        const int c = j >> 6, k = j & 63;
        ushort_t h, l; split2(wo[k * ODIM + c], h, l);
        woT_hi[j] = h; woT_lo[j] = l;
    }
}

// ---------------- Kernel 1: QKV projection (MFMA hi/lo) ----------------
// grid 1536 x 256. row_tile = bb & 511 (stride-512 siblings share an XCD ->
// L2-local x reuse); ctid = (bb>>9)*4 + wv. q is pre-scaled by log2e.
__global__ __launch_bounds__(256) void qkv_kernel(
    const float* __restrict__ x,
    const ushort_t* __restrict__ wT_hi, const ushort_t* __restrict__ wT_lo,
    const float* __restrict__ b,
    ushort_t* __restrict__ q_hi, ushort_t* __restrict__ q_lo,
    ushort_t* __restrict__ k_hi, ushort_t* __restrict__ k_lo,
    ushort_t* __restrict__ vT)
{
    const int tid = threadIdx.x;
    const int wv = tid >> 6, lane = tid & 63, g = lane >> 4, i = lane & 15;
    const int bb = (int)blockIdx.x;
    const int R0 = (bb & 511) * 16;
    const int ctid = (bb >> 9) * 4 + wv;   // 0..11
    const f32x4 zero4 = {0.f, 0.f, 0.f, 0.f};
    f32x4 acc = zero4;
    const float* xp = &x[(size_t)(R0 + i) * DM + g * 8];
    const ushort_t* bhp = &wT_hi[(ctid * 16 + i) * DM + g * 8];
    const ushort_t* blp = &wT_lo[(ctid * 16 + i) * DM + g * 8];

    for (int kc = 0; kc < 32; ++kc) {
        const float4 xa = *(const float4*)(xp + kc * 32);
        const float4 xb = *(const float4*)(xp + kc * 32 + 4);
        const float xe[8] = {xa.x, xa.y, xa.z, xa.w, xb.x, xb.y, xb.z, xb.w};
        union { short8 v; ushort_t u[8]; } ah, al;
#pragma unroll
        for (int j = 0; j < 8; ++j) { split2(xe[j], ah.u[j], al.u[j]); }
        const short8 bh = *(const short8*)(bhp + kc * 32);
        const short8 bl = *(const short8*)(blp + kc * 32);
        acc = MFMA16(ah.v, bh, acc);
        acc = MFMA16(ah.v, bl, acc);
        acc = MFMA16(al.v, bh, acc);
    }
    const int c = ctid * 16 + i;
    const float bias = b[c];
    if (ctid < 4) {          // q: pre-scale by log2e (softmax in exp2 domain)
#pragma unroll
        for (int reg = 0; reg < 4; ++reg) {
            ushort_t h, l; split2((acc[reg] + bias) * LOG2E, h, l);
            q_hi[(R0 + 4 * g + reg) * KD + c] = h;
            q_lo[(R0 + 4 * g + reg) * KD + c] = l;
        }
    } else if (ctid < 8) {   // k
        const int c2 = c - 64;
#pragma unroll
        for (int reg = 0; reg < 4; ++reg) {
            ushort_t h, l; split2(acc[reg] + bias, h, l);
            k_hi[(R0 + 4 * g + reg) * KD + c2] = h;
            k_lo[(R0 + 4 * g + reg) * KD + c2] = l;
        }
    } else {                 // v -> transposed bf16
        union { ushort_t u[4]; uint2 v; } pk;
#pragma unroll
        for (int reg = 0; reg < 4; ++reg) pk.u[reg] = rne(acc[reg] + bias);
        *(uint2*)&vT[(size_t)(c - 128) * N_TOK + R0 + 4 * g] = pk.v;
    }
}

// ---------------- Kernel 2: LDS-pipelined split-K causal flash attention ----------------
// grid 512 x 256. Block = 64 q-rows (gb) x split-s quarter; wave wv owns rows
// gb*64+wv*16. K(hi,lo) double-buffered in LDS via global_load_lds, shared by
// all 4 waves (4x less L2 traffic); counted vmcnt keeps next-tile stage + V
// prefetch in flight across the 2 barriers/tile (T3+T4+T14). LDS 16B slots are
// XOR-swizzled with sw=((r&3)<<1)|((r>>3)&1) so the permuted-koff fragment rows
// ({0-3,8-11,16-19,24-27}) spread 2-per-bank-quad (2-way = free). Each wave
// owns a full (qt,s) partial -> no cross-wave combine; Opart/MLpart layout
// identical to previous version (proj_kernel unchanged).
// Block pairing: blocks n and n+256 share a CU; gb = half ? q2 : 127-q2 makes
// each CU's two chunks sum to a constant ~32 tiles.
__global__ __launch_bounds__(256) void attn_kernel(
    const ushort_t* __restrict__ q_hi, const ushort_t* __restrict__ q_lo,
    const ushort_t* __restrict__ k_hi, const ushort_t* __restrict__ k_lo,
    const ushort_t* __restrict__ vT,
    float* __restrict__ Opart, float* __restrict__ MLpart,
    const int* __restrict__ causal_p)
{
    __shared__ ushort_t Kls[2][2][4096];   // [buf][hi/lo][64 keys x 64 dims], 32 KB

    const int tid = threadIdx.x;
    const int wv = tid >> 6, lane = tid & 63, g = lane >> 4, i = lane & 15;
    const int causal = *causal_p;
    const f32x4 zero4 = {0.f, 0.f, 0.f, 0.f};
    const int ibase = ((i >> 2) << 3) + (i & 3);

    const int wu = (int)blockIdx.x;
    const int half = wu >> 8, q2 = (wu & 255) >> 2, s = wu & 3;
    const int gb = half ? q2 : 127 - q2;      // balanced heavy/light CU pairing
    const int R0w = (gb << 6) + (wv << 4);    // wave's q-row base
    const int nkt = causal ? gb + 1 : (N_TOK / 64);
    const int c0 = (s * nkt) >> 2, c1 = ((s + 1) * nkt) >> 2;

    const short8 qh0 = *(const short8*)&q_hi[(R0w + i) * KD + g * 8];
    const short8 qh1 = *(const short8*)&q_hi[(R0w + i) * KD + 32 + g * 8];
    const short8 ql0 = *(const short8*)&q_lo[(R0w + i) * KD + g * 8];
    const short8 ql1 = *(const short8*)&q_lo[(R0w + i) * KD + 32 + g * 8];

    // stage K hi/lo tile t into buffer nb: wave wv covers 1KB chunks {wv,wv+4}
    // of each 8KB matrix. LDS write is linear (HW); the global SOURCE slot is
    // pre-permuted so that reads can apply the same XOR (rule #21).
    const int srow = lane >> 3;      // row within chunk (0..7)
    const int sslot = lane & 7;      // 16B slot within row
    auto stageK = [&](int nb, int t) {
        const int kb2 = t << 6;
#pragma unroll
        for (int h = 0; h < 2; ++h) {
            const int ch = wv + (h << 2);
            const int row = (ch << 3) + srow;
            const int sw = ((row & 3) << 1) | ((row >> 3) & 1);
            const size_t src = (size_t)(kb2 + row) * KD + ((sslot ^ sw) << 3);
            gld_lds16(&k_hi[src], &Kls[nb][0][ch << 9]);
            gld_lds16(&k_lo[src], &Kls[nb][1][ch << 9]);
        }
    };

    f32x4 o4[4] = {zero4, zero4, zero4, zero4};
    float runm = -1e30f, runl = 0.f;

    if (c0 < c1) stageK(0, c0);   // prologue: 4 lds-DMA issues/wave

    for (int t = c0; t < c1; ++t) {
        const int cur = (t - c0) & 1;
        const int kb = t << 6;
        const bool more = (t + 1 < c1);

        // V for current tile: issue now, consume after softmax (latency hidden
        // under QK^T + softmax).
        short8 va0[4], va1[4];
#pragma unroll
        for (int ct2 = 0; ct2 < 4; ++ct2) {
            const size_t vrow = (size_t)(ct2 * 16 + i) * N_TOK + kb;
            va0[ct2] = *(const short8*)&vT[vrow + g * 8];
            va1[ct2] = *(const short8*)&vT[vrow + 32 + g * 8];
        }
        if (more) {
            stageK(cur ^ 1, t + 1);                       // next tile in flight
            asm volatile("s_waitcnt vmcnt(12)" ::: "memory");  // own K(cur) done
        } else {
            asm volatile("s_waitcnt vmcnt(8)" ::: "memory");
        }
        __builtin_amdgcn_s_barrier();   // K(cur) staged by all 4 waves

        f32x4 s4[4];
#pragma unroll
        for (int ct = 0; ct < 4; ++ct) {
            const int r = ((ct & 1) << 2) + ((ct >> 1) << 5) + ibase;
            const int sw = ((r & 3) << 1) | ((r >> 3) & 1);
            const ushort_t* khp = &Kls[cur][0][r << 6];
            const ushort_t* klp = &Kls[cur][1][r << 6];
            const short8 kh0 = *(const short8*)&khp[(g ^ sw) << 3];
            const short8 kh1 = *(const short8*)&khp[((g + 4) ^ sw) << 3];
            const short8 kl0 = *(const short8*)&klp[(g ^ sw) << 3];
            const short8 kl1 = *(const short8*)&klp[((g + 4) ^ sw) << 3];
            f32x4 a = MFMA16(kh0, qh0, zero4);
            a = MFMA16(kh1, qh1, a);
            a = MFMA16(kh0, ql0, a);
            a = MFMA16(kh1, ql1, a);
            a = MFMA16(kl0, qh0, a);
            a = MFMA16(kl1, qh1, a);
            s4[ct] = a;
        }
        // my LDS reads have landed in regs -> safe for others to overwrite buf
        asm volatile("s_waitcnt lgkmcnt(0)" ::: "memory");
        __builtin_amdgcn_s_barrier();

        if (causal && (kb + 64 > R0w)) {  // diagonal tile only
#pragma unroll
            for (int ct = 0; ct < 4; ++ct) {
                const int kba = kb + ((ct & 1) << 2) + ((ct >> 1) << 5);
#pragma unroll
                for (int reg = 0; reg < 4; ++reg) {
                    const int key = kba + (g << 3) + reg;
                    s4[ct][reg] = (key <= R0w + i) ? s4[ct][reg] : -1e30f;
                }
            }
        }
        // online softmax: lane owns qrow i; scalar state
        float mx = -1e30f;
#pragma unroll
        for (int ct = 0; ct < 4; ++ct)
#pragma unroll
            for (int reg = 0; reg < 4; ++reg) mx = fmaxf(mx, s4[ct][reg]);
        mx = fmaxf(mx, __shfl_xor(mx, 16));
        mx = fmaxf(mx, __shfl_xor(mx, 32));
        const float nm = fmaxf(runm, mx);
        const float al = ex2(runm - nm);
        runm = nm;
        float rs = 0.f;
#pragma unroll
        for (int ct = 0; ct < 4; ++ct)
#pragma unroll
            for (int reg = 0; reg < 4; ++reg) {
                const float p = ex2(s4[ct][reg] - nm);
                s4[ct][reg] = p;
                rs += p;
            }
        rs += __shfl_xor(rs, 16);
        rs += __shfl_xor(rs, 32);
        runl = runl * al + rs;
#pragma unroll
        for (int ct2 = 0; ct2 < 4; ++ct2)
#pragma unroll
            for (int reg = 0; reg < 4; ++reg) o4[ct2][reg] *= al;
        // P^T B-frags: pure register repack
        short8 pb0, pb1;
        {
            union { unsigned w[4]; short8 v; } u;
            u.w[0] = bfpack(s4[0][0], s4[0][1]); u.w[1] = bfpack(s4[0][2], s4[0][3]);
            u.w[2] = bfpack(s4[1][0], s4[1][1]); u.w[3] = bfpack(s4[1][2], s4[1][3]);
            pb0 = u.v;
            u.w[0] = bfpack(s4[2][0], s4[2][1]); u.w[1] = bfpack(s4[2][2], s4[2][3]);
            u.w[2] = bfpack(s4[3][0], s4[3][1]); u.w[3] = bfpack(s4[3][2], s4[3][3]);
            pb1 = u.v;
        }
        // V landed (leaves next-tile K stage in flight when more)
        if (more) asm volatile("s_waitcnt vmcnt(4)" ::: "memory");
        else      asm volatile("s_waitcnt vmcnt(0)" ::: "memory");
#pragma unroll
        for (int ct2 = 0; ct2 < 4; ++ct2) {
            o4[ct2] = MFMA16(va0[ct2], pb0, o4[ct2]);
            o4[ct2] = MFMA16(va1[ct2], pb1, o4[ct2]);
        }
    }

    // epilogue: each wave owns the full (qt = gb*4+wv, s) partial
    const int qt = (gb << 2) + wv;
    const int pidx = (qt << 2) + s;
#pragma unroll
    for (int ct2 = 0; ct2 < 4; ++ct2)
#pragma unroll
        for (int reg = 0; reg < 4; ++reg) {
            const int d = ct2 * 16 + 4 * g + reg;
            Opart[((size_t)pidx * 16 + i) * 64 + d] = o4[ct2][reg];
        }
    if (lane < 16) {
        MLpart[pidx * 32 + lane] = runm;
        MLpart[pidx * 32 + 16 + lane] = runl;
    }
}

// ---------------- Kernel 3: fused split-K merge + output projection ----------------
// grid 2048 x 256. Block (qtile=b>>2, qa=b&3): merge 4 partials of qtile into
// LDS ao (bf16 hi/lo), then MFMA project col quarter qa.
__global__ __launch_bounds__(256) void proj_kernel(
    const float* __restrict__ Opart, const float* __restrict__ MLpart,
    const ushort_t* __restrict__ woT_hi, const ushort_t* __restrict__ woT_lo,
    const float* __restrict__ bo, float* __restrict__ out)
{
    __shared__ ushort_t aoh[16 * 72];
    __shared__ ushort_t aol[16 * 72];
    const int tid = threadIdx.x;
    const int wv = tid >> 6, lane = tid & 63, g = lane >> 4, i = lane & 15;
    const int bb = (int)blockIdx.x;
    const int qtile = bb >> 2, qa = bb & 3;
    const int R0 = qtile << 4;
    const f32x4 zero4 = {0.f, 0.f, 0.f, 0.f};
    {
        const int d = tid & 63, rb2 = (tid >> 6) << 2;
#pragma unroll
        for (int rr = 0; rr < 4; ++rr) {
            const int r = rb2 + rr;
            float m[4], l[4];
#pragma unroll
            for (int s2 = 0; s2 < 4; ++s2) {
                m[s2] = MLpart[((qtile << 2) + s2) * 32 + r];
                l[s2] = MLpart[((qtile << 2) + s2) * 32 + 16 + r];
            }
            const float M = fmaxf(fmaxf(m[0], m[1]), fmaxf(m[2], m[3]));
            float den = 0.f, O = 0.f;
#pragma unroll
            for (int s2 = 0; s2 < 4; ++s2) {
                const float e = ex2(m[s2] - M);
                den += l[s2] * e;
                O += Opart[((size_t)((qtile << 2) + s2) * 16 + r) * 64 + d] * e;
            }
            ushort_t h, lo2; split2(O / den, h, lo2);
            aoh[r * 72 + d] = h;
            aol[r * 72 + d] = lo2;
        }
    }
    __syncthreads();
    {
        const short8 ah0 = *(const short8*)&aoh[i * 72 + g * 8];
        const short8 ah1 = *(const short8*)&aoh[i * 72 + 32 + g * 8];
        const short8 al0 = *(const short8*)&aol[i * 72 + g * 8];
        const short8 al1 = *(const short8*)&aol[i * 72 + 32 + g * 8];
#pragma unroll
        for (int cc = 0; cc < 4; ++cc) {
            const int col = (qa << 8) + ((wv << 2) + cc) * 16 + i;
            const short8 bh0 = *(const short8*)&woT_hi[col * KD + g * 8];
            const short8 bh1 = *(const short8*)&woT_hi[col * KD + 32 + g * 8];
            const short8 bl0 = *(const short8*)&woT_lo[col * KD + g * 8];
            const short8 bl1 = *(const short8*)&woT_lo[col * KD + 32 + g * 8];
            f32x4 acc = MFMA16(ah0, bh0, zero4);
            acc = MFMA16(ah1, bh1, acc);
            acc = MFMA16(ah0, bl0, acc);
            acc = MFMA16(ah1, bl1, acc);
            acc = MFMA16(al0, bh0, acc);
            acc = MFMA16(al1, bh1, acc);
            const float bias = bo[col];
#pragma unroll
            for (int reg = 0; reg < 4; ++reg)
                out[(size_t)(R0 + 4 * g + reg) * ODIM + col] = acc[reg] + bias;
        }
    }
}

extern "C" void kernel_launch(void* const* d_in, const int* in_sizes, int n_in,
                              void* d_out, int out_size, void* d_ws, size_t ws_size,
                              hipStream_t stream) {
    const float* x     = (const float*)d_in[0];
    const float* w_qkv = (const float*)d_in[1];
    const float* b_qkv = (const float*)d_in[2];
    const float* w_out = (const float*)d_in[3];
    const float* b_out = (const float*)d_in[4];
    const int* causal  = (const int*)d_in[5];
    float* out         = (float*)d_out;

    char* ws = (char*)d_ws;
    ushort_t* wT_hi  = (ushort_t*)(ws);                    // 384 KB
    ushort_t* wT_lo  = (ushort_t*)(ws + 393216);           // 384 KB
    ushort_t* woT_hi = (ushort_t*)(ws + 786432);           // 128 KB
    ushort_t* woT_lo = (ushort_t*)(ws + 917504);           // 128 KB -> 1 MB
    ushort_t* q_hi   = (ushort_t*)(ws + (1u << 20));
    ushort_t* q_lo   = (ushort_t*)(ws + (2u << 20));
    ushort_t* k_hi   = (ushort_t*)(ws + (3u << 20));
    ushort_t* k_lo   = (ushort_t*)(ws + (4u << 20));
    ushort_t* vT     = (ushort_t*)(ws + (5u << 20));       // -> 6 MB
    float*    Opart  = (float*)(ws + (6u << 20));          // 8 MB -> 14 MB
    float*    MLpart = (float*)(ws + (14u << 20));         // 256 KB

    prep_kernel<<<1024, 256, 0, stream>>>(w_qkv, w_out, wT_hi, wT_lo, woT_hi, woT_lo);
    qkv_kernel<<<1536, 256, 0, stream>>>(x, wT_hi, wT_lo, b_qkv, q_hi, q_lo, k_hi, k_lo, vT);
    attn_kernel<<<512, 256, 0, stream>>>(q_hi, q_lo, k_hi, k_lo, vT, Opart, MLpart, causal);
    proj_kernel<<<2048, 256, 0, stream>>>(Opart, MLpart, woT_hi, woT_lo, b_out, out);
}

// Round 2
// 252.737 us; speedup vs baseline: 1.1602x; 1.0653x over previous
//
#include <hip/hip_runtime.h>
#include <hip/hip_bf16.h>

#define N_TOK 8192
#define DM 1024
#define KD 64
#define ODIM 1024
#define LOG2E 1.4426950408889634f

typedef unsigned short ushort_t;
typedef __attribute__((ext_vector_type(8))) short short8;
typedef __attribute__((ext_vector_type(4))) float f32x4;

#define MFMA16(a, b, c) __builtin_amdgcn_mfma_f32_16x16x32_bf16((a), (b), (c), 0, 0, 0)

__device__ __forceinline__ float ex2(float x) {
#if __has_builtin(__builtin_amdgcn_exp2f)
    return __builtin_amdgcn_exp2f(x);
#else
    return exp2f(x);
#endif
}
// RNE float->bf16 (finite inputs)
__device__ __forceinline__ ushort_t rne(float x) {
    unsigned u = __float_as_uint(x);
    u += 0x7fffu + ((u >> 16) & 1u);
    return (ushort_t)(u >> 16);
}
__device__ __forceinline__ float ubf(ushort_t h) {
    return __uint_as_float(((unsigned)h) << 16);
}
__device__ __forceinline__ void split2(float x, ushort_t& hi, ushort_t& lo) {
    hi = rne(x);
    lo = rne(x - ubf(hi));
}
__device__ __forceinline__ unsigned bfpack(float a, float b) {
    unsigned ua = __float_as_uint(a); ua += 0x7fffu + ((ua >> 16) & 1u);
    unsigned ub = __float_as_uint(b); ub += 0x7fffu + ((ub >> 16) & 1u);
    return (ua >> 16) | (ub & 0xffff0000u);
}
// async global->LDS, 16B per lane; lds dst must be wave-uniform base (+lane*16 implicit)
__device__ __forceinline__ void gld_lds16(const void* g, void* l) {
    __builtin_amdgcn_global_load_lds(
        (const __attribute__((address_space(1))) unsigned int*)g,
        (__attribute__((address_space(3))) unsigned int*)l, 16, 0, 0);
}

// ---------------- Kernel 0: weight transpose + x hi/lo pre-split ----------------
// grid 5120 x 256. idx<192K: w_qkv transpose+split; <256K: w_out; rest: x
// pre-split (8 elems/thread) so qkv's inner loop has NO VALU conversion chain.
__global__ __launch_bounds__(256) void prep_kernel(
    const float* __restrict__ wq, const float* __restrict__ wo,
    const float* __restrict__ x,
    ushort_t* __restrict__ wT_hi, ushort_t* __restrict__ wT_lo,
    ushort_t* __restrict__ woT_hi, ushort_t* __restrict__ woT_lo,
    ushort_t* __restrict__ x_hi, ushort_t* __restrict__ x_lo)
{
    const int idx = blockIdx.x * 256 + threadIdx.x;
    if (idx < 192 * 1024) {
        const int c = idx >> 10, k = idx & 1023;
        ushort_t h, l; split2(wq[k * 192 + c], h, l);
        wT_hi[idx] = h; wT_lo[idx] = l;
    } else if (idx < 256 * 1024) {
        const int j = idx - 192 * 1024;
        const int c = j >> 6, k = j & 63;
        ushort_t h, l; split2(wo[k * ODIM + c], h, l);
        woT_hi[j] = h; woT_lo[j] = l;
    } else {
        const size_t j = (size_t)(idx - 256 * 1024) * 8;   // 1M threads x 8 elems
        const float4 xa = *(const float4*)&x[j];
        const float4 xb = *(const float4*)&x[j + 4];
        const float xe[8] = {xa.x, xa.y, xa.z, xa.w, xb.x, xb.y, xb.z, xb.w};
        union { short8 v; ushort_t u[8]; } hh, ll;
#pragma unroll
        for (int e = 0; e < 8; ++e) { split2(xe[e], hh.u[e], ll.u[e]); }
        *(short8*)&x_hi[j] = hh.v;
        *(short8*)&x_lo[j] = ll.v;
    }
}

// ---------------- Kernel 1: QKV projection (pure bf16 MFMA hi/lo) ----------------
// grid 768 x 256. Block = 32 rows (rp = bb&255; stride-256 keeps ctid-group
// siblings on the same XCD residue for L2-local x reuse) x one ctid group
// (bb>>8). Wave wv owns ctid = (bb>>8)*4+wv for BOTH 16-row tiles: weight
// fragments load once, feed 2 A-frags -> halves weight L2 traffic, 6 MFMA +
// 6 loads/iter, no VALU on the critical path (x pre-split in prep).
__global__ __launch_bounds__(256) void qkv_kernel(
    const ushort_t* __restrict__ x_hi, const ushort_t* __restrict__ x_lo,
    const ushort_t* __restrict__ wT_hi, const ushort_t* __restrict__ wT_lo,
    const float* __restrict__ b,
    ushort_t* __restrict__ q_hi, ushort_t* __restrict__ q_lo,
    ushort_t* __restrict__ k_hi, ushort_t* __restrict__ k_lo,
    ushort_t* __restrict__ vT)
{
    const int tid = threadIdx.x;
    const int wv = tid >> 6, lane = tid & 63, g = lane >> 4, i = lane & 15;
    const int bb = (int)blockIdx.x;
    const int R0 = (bb & 255) * 32;
    const int ctid = (bb >> 8) * 4 + wv;   // 0..11
    const f32x4 zero4 = {0.f, 0.f, 0.f, 0.f};
    f32x4 acc0 = zero4, acc1 = zero4;
    const ushort_t* xh0 = &x_hi[(size_t)(R0 + i) * DM + g * 8];
    const ushort_t* xl0 = &x_lo[(size_t)(R0 + i) * DM + g * 8];
    const ushort_t* xh1 = xh0 + 16 * DM;
    const ushort_t* xl1 = xl0 + 16 * DM;
    const ushort_t* bhp = &wT_hi[(ctid * 16 + i) * DM + g * 8];
    const ushort_t* blp = &wT_lo[(ctid * 16 + i) * DM + g * 8];

#pragma unroll 4
    for (int kc = 0; kc < 32; ++kc) {
        const short8 a0h = *(const short8*)(xh0 + kc * 32);
        const short8 a0l = *(const short8*)(xl0 + kc * 32);
        const short8 a1h = *(const short8*)(xh1 + kc * 32);
        const short8 a1l = *(const short8*)(xl1 + kc * 32);
        const short8 bh  = *(const short8*)(bhp + kc * 32);
        const short8 bl  = *(const short8*)(blp + kc * 32);
        acc0 = MFMA16(a0h, bh, acc0);
        acc0 = MFMA16(a0h, bl, acc0);
        acc0 = MFMA16(a0l, bh, acc0);
        acc1 = MFMA16(a1h, bh, acc1);
        acc1 = MFMA16(a1h, bl, acc1);
        acc1 = MFMA16(a1l, bh, acc1);
    }
    const int c = ctid * 16 + i;
    const float bias = b[c];
    if (ctid < 4) {          // q: pre-scale by log2e (softmax in exp2 domain)
#pragma unroll
        for (int reg = 0; reg < 4; ++reg) {
            ushort_t h, l;
            split2((acc0[reg] + bias) * LOG2E, h, l);
            q_hi[(R0 + 4 * g + reg) * KD + c] = h;
            q_lo[(R0 + 4 * g + reg) * KD + c] = l;
            split2((acc1[reg] + bias) * LOG2E, h, l);
            q_hi[(R0 + 16 + 4 * g + reg) * KD + c] = h;
            q_lo[(R0 + 16 + 4 * g + reg) * KD + c] = l;
        }
    } else if (ctid < 8) {   // k
        const int c2 = c - 64;
#pragma unroll
        for (int reg = 0; reg < 4; ++reg) {
            ushort_t h, l;
            split2(acc0[reg] + bias, h, l);
            k_hi[(R0 + 4 * g + reg) * KD + c2] = h;
            k_lo[(R0 + 4 * g + reg) * KD + c2] = l;
            split2(acc1[reg] + bias, h, l);
            k_hi[(R0 + 16 + 4 * g + reg) * KD + c2] = h;
            k_lo[(R0 + 16 + 4 * g + reg) * KD + c2] = l;
        }
    } else {                 // v -> transposed bf16
        union { ushort_t u[4]; uint2 v; } pk;
#pragma unroll
        for (int reg = 0; reg < 4; ++reg) pk.u[reg] = rne(acc0[reg] + bias);
        *(uint2*)&vT[(size_t)(c - 128) * N_TOK + R0 + 4 * g] = pk.v;
#pragma unroll
        for (int reg = 0; reg < 4; ++reg) pk.u[reg] = rne(acc1[reg] + bias);
        *(uint2*)&vT[(size_t)(c - 128) * N_TOK + R0 + 16 + 4 * g] = pk.v;
    }
}

// ---------------- Kernel 2: LDS-pipelined split-K causal flash attention ----------------
// grid 512 x 256. Block = 64 q-rows (gb) x split-s quarter; wave wv owns rows
// gb*64+wv*16. K(hi,lo) double-buffered in LDS via global_load_lds, shared by
// all 4 waves (4x less L2 traffic); counted vmcnt keeps next-tile stage + V
// prefetch in flight across the 2 barriers/tile (T3+T4+T14). LDS 16B slots are
// XOR-swizzled with sw=((r&3)<<1)|((r>>3)&1) so the permuted-koff fragment rows
// ({0-3,8-11,16-19,24-27}) spread 2-per-bank-quad (2-way = free). Each wave
// owns a full (qt,s) partial -> no cross-wave combine; Opart/MLpart layout
// identical to previous version (proj_kernel unchanged).
// Block pairing: blocks n and n+256 share a CU; gb = half ? q2 : 127-q2 makes
// each CU's two chunks sum to a constant ~32 tiles.
__global__ __launch_bounds__(256) void attn_kernel(
    const ushort_t* __restrict__ q_hi, const ushort_t* __restrict__ q_lo,
    const ushort_t* __restrict__ k_hi, const ushort_t* __restrict__ k_lo,
    const ushort_t* __restrict__ vT,
    float* __restrict__ Opart, float* __restrict__ MLpart,
    const int* __restrict__ causal_p)
{
    __shared__ ushort_t Kls[2][2][4096];   // [buf][hi/lo][64 keys x 64 dims], 32 KB

    const int tid = threadIdx.x;
    const int wv = tid >> 6, lane = tid & 63, g = lane >> 4, i = lane & 15;
    const int causal = *causal_p;
    const f32x4 zero4 = {0.f, 0.f, 0.f, 0.f};
    const int ibase = ((i >> 2) << 3) + (i & 3);

    const int wu = (int)blockIdx.x;
    const int half = wu >> 8, q2 = (wu & 255) >> 2, s = wu & 3;
    const int gb = half ? q2 : 127 - q2;      // balanced heavy/light CU pairing
    const int R0w = (gb << 6) + (wv << 4);    // wave's q-row base
    const int nkt = causal ? gb + 1 : (N_TOK / 64);
    const int c0 = (s * nkt) >> 2, c1 = ((s + 1) * nkt) >> 2;

    const short8 qh0 = *(const short8*)&q_hi[(R0w + i) * KD + g * 8];
    const short8 qh1 = *(const short8*)&q_hi[(R0w + i) * KD + 32 + g * 8];
    const short8 ql0 = *(const short8*)&q_lo[(R0w + i) * KD + g * 8];
    const short8 ql1 = *(const short8*)&q_lo[(R0w + i) * KD + 32 + g * 8];

    // stage K hi/lo tile t into buffer nb: wave wv covers 1KB chunks {wv,wv+4}
    // of each 8KB matrix. LDS write is linear (HW); the global SOURCE slot is
    // pre-permuted so that reads can apply the same XOR (rule #21).
    const int srow = lane >> 3;      // row within chunk (0..7)
    const int sslot = lane & 7;      // 16B slot within row
    auto stageK = [&](int nb, int t) {
        const int kb2 = t << 6;
#pragma unroll
        for (int h = 0; h < 2; ++h) {
            const int ch = wv + (h << 2);
            const int row = (ch << 3) + srow;
            const int sw = ((row & 3) << 1) | ((row >> 3) & 1);
            const size_t src = (size_t)(kb2 + row) * KD + ((sslot ^ sw) << 3);
            gld_lds16(&k_hi[src], &Kls[nb][0][ch << 9]);
            gld_lds16(&k_lo[src], &Kls[nb][1][ch << 9]);
        }
    };

    f32x4 o4[4] = {zero4, zero4, zero4, zero4};
    float runm = -1e30f, runl = 0.f;

    if (c0 < c1) stageK(0, c0);   // prologue: 4 lds-DMA issues/wave

    for (int t = c0; t < c1; ++t) {
        const int cur = (t - c0) & 1;
        const int kb = t << 6;
        const bool more = (t + 1 < c1);

        // V for current tile: issue now, consume after softmax (latency hidden
        // under QK^T + softmax).
        short8 va0[4], va1[4];
#pragma unroll
        for (int ct2 = 0; ct2 < 4; ++ct2) {
            const size_t vrow = (size_t)(ct2 * 16 + i) * N_TOK + kb;
            va0[ct2] = *(const short8*)&vT[vrow + g * 8];
            va1[ct2] = *(const short8*)&vT[vrow + 32 + g * 8];
        }
        if (more) {
            stageK(cur ^ 1, t + 1);                       // next tile in flight
            asm volatile("s_waitcnt vmcnt(12)" ::: "memory");  // own K(cur) done
        } else {
            asm volatile("s_waitcnt vmcnt(8)" ::: "memory");
        }
        __builtin_amdgcn_s_barrier();   // K(cur) staged by all 4 waves

        f32x4 s4[4];
#pragma unroll
        for (int ct = 0; ct < 4; ++ct) {
            const int r = ((ct & 1) << 2) + ((ct >> 1) << 5) + ibase;
            const int sw = ((r & 3) << 1) | ((r >> 3) & 1);
            const ushort_t* khp = &Kls[cur][0][r << 6];
            const ushort_t* klp = &Kls[cur][1][r << 6];
            const short8 kh0 = *(const short8*)&khp[(g ^ sw) << 3];
            const short8 kh1 = *(const short8*)&khp[((g + 4) ^ sw) << 3];
            const short8 kl0 = *(const short8*)&klp[(g ^ sw) << 3];
            const short8 kl1 = *(const short8*)&klp[((g + 4) ^ sw) << 3];
            f32x4 a = MFMA16(kh0, qh0, zero4);
            a = MFMA16(kh1, qh1, a);
            a = MFMA16(kh0, ql0, a);
            a = MFMA16(kh1, ql1, a);
            a = MFMA16(kl0, qh0, a);
            a = MFMA16(kl1, qh1, a);
            s4[ct] = a;
        }
        // my LDS reads have landed in regs -> safe for others to overwrite buf
        asm volatile("s_waitcnt lgkmcnt(0)" ::: "memory");
        __builtin_amdgcn_s_barrier();

        if (causal && (kb + 64 > R0w)) {  // diagonal tile only
#pragma unroll
            for (int ct = 0; ct < 4; ++ct) {
                const int kba = kb + ((ct & 1) << 2) + ((ct >> 1) << 5);
#pragma unroll
                for (int reg = 0; reg < 4; ++reg) {
                    const int key = kba + (g << 3) + reg;
                    s4[ct][reg] = (key <= R0w + i) ? s4[ct][reg] : -1e30f;
                }
            }
        }
        // online softmax: lane owns qrow i; scalar state
        float mx = -1e30f;
#pragma unroll
        for (int ct = 0; ct < 4; ++ct)
#pragma unroll
            for (int reg = 0; reg < 4; ++reg) mx = fmaxf(mx, s4[ct][reg]);
        mx = fmaxf(mx, __shfl_xor(mx, 16));
        mx = fmaxf(mx, __shfl_xor(mx, 32));
        const float nm = fmaxf(runm, mx);
        const float al = ex2(runm - nm);
        runm = nm;
        float rs = 0.f;
#pragma unroll
        for (int ct = 0; ct < 4; ++ct)
#pragma unroll
            for (int reg = 0; reg < 4; ++reg) {
                const float p = ex2(s4[ct][reg] - nm);
                s4[ct][reg] = p;
                rs += p;
            }
        rs += __shfl_xor(rs, 16);
        rs += __shfl_xor(rs, 32);
        runl = runl * al + rs;
#pragma unroll
        for (int ct2 = 0; ct2 < 4; ++ct2)
#pragma unroll
            for (int reg = 0; reg < 4; ++reg) o4[ct2][reg] *= al;
        // P^T B-frags: pure register repack
        short8 pb0, pb1;
        {
            union { unsigned w[4]; short8 v; } u;
            u.w[0] = bfpack(s4[0][0], s4[0][1]); u.w[1] = bfpack(s4[0][2], s4[0][3]);
            u.w[2] = bfpack(s4[1][0], s4[1][1]); u.w[3] = bfpack(s4[1][2], s4[1][3]);
            pb0 = u.v;
            u.w[0] = bfpack(s4[2][0], s4[2][1]); u.w[1] = bfpack(s4[2][2], s4[2][3]);
            u.w[2] = bfpack(s4[3][0], s4[3][1]); u.w[3] = bfpack(s4[3][2], s4[3][3]);
            pb1 = u.v;
        }
        // V landed (leaves next-tile K stage in flight when more)
        if (more) asm volatile("s_waitcnt vmcnt(4)" ::: "memory");
        else      asm volatile("s_waitcnt vmcnt(0)" ::: "memory");
#pragma unroll
        for (int ct2 = 0; ct2 < 4; ++ct2) {
            o4[ct2] = MFMA16(va0[ct2], pb0, o4[ct2]);
            o4[ct2] = MFMA16(va1[ct2], pb1, o4[ct2]);
        }
    }

    // epilogue: each wave owns the full (qt = gb*4+wv, s) partial
    const int qt = (gb << 2) + wv;
    const int pidx = (qt << 2) + s;
#pragma unroll
    for (int ct2 = 0; ct2 < 4; ++ct2)
#pragma unroll
        for (int reg = 0; reg < 4; ++reg) {
            const int d = ct2 * 16 + 4 * g + reg;
            Opart[((size_t)pidx * 16 + i) * 64 + d] = o4[ct2][reg];
        }
    if (lane < 16) {
        MLpart[pidx * 32 + lane] = runm;
        MLpart[pidx * 32 + 16 + lane] = runl;
    }
}

// ---------------- Kernel 3: fused split-K merge + output projection ----------------
// grid 2048 x 256. Block (qtile=b>>2, qa=b&3): merge 4 partials of qtile into
// LDS ao (bf16 hi/lo), then MFMA project col quarter qa.
__global__ __launch_bounds__(256) void proj_kernel(
    const float* __restrict__ Opart, const float* __restrict__ MLpart,
    const ushort_t* __restrict__ woT_hi, const ushort_t* __restrict__ woT_lo,
    const float* __restrict__ bo, float* __restrict__ out)
{
    __shared__ ushort_t aoh[16 * 72];
    __shared__ ushort_t aol[16 * 72];
    const int tid = threadIdx.x;
    const int wv = tid >> 6, lane = tid & 63, g = lane >> 4, i = lane & 15;
    const int bb = (int)blockIdx.x;
    const int qtile = bb >> 2, qa = bb & 3;
    const int R0 = qtile << 4;
    const f32x4 zero4 = {0.f, 0.f, 0.f, 0.f};
    {
        const int d = tid & 63, rb2 = (tid >> 6) << 2;
#pragma unroll
        for (int rr = 0; rr < 4; ++rr) {
            const int r = rb2 + rr;
            float m[4], l[4];
#pragma unroll
            for (int s2 = 0; s2 < 4; ++s2) {
                m[s2] = MLpart[((qtile << 2) + s2) * 32 + r];
                l[s2] = MLpart[((qtile << 2) + s2) * 32 + 16 + r];
            }
            const float M = fmaxf(fmaxf(m[0], m[1]), fmaxf(m[2], m[3]));
            float den = 0.f, O = 0.f;
#pragma unroll
            for (int s2 = 0; s2 < 4; ++s2) {
                const float e = ex2(m[s2] - M);
                den += l[s2] * e;
                O += Opart[((size_t)((qtile << 2) + s2) * 16 + r) * 64 + d] * e;
            }
            ushort_t h, lo2; split2(O / den, h, lo2);
            aoh[r * 72 + d] = h;
            aol[r * 72 + d] = lo2;
        }
    }
    __syncthreads();
    {
        const short8 ah0 = *(const short8*)&aoh[i * 72 + g * 8];
        const short8 ah1 = *(const short8*)&aoh[i * 72 + 32 + g * 8];
        const short8 al0 = *(const short8*)&aol[i * 72 + g * 8];
        const short8 al1 = *(const short8*)&aol[i * 72 + 32 + g * 8];
#pragma unroll
        for (int cc = 0; cc < 4; ++cc) {
            const int col = (qa << 8) + ((wv << 2) + cc) * 16 + i;
            const short8 bh0 = *(const short8*)&woT_hi[col * KD + g * 8];
            const short8 bh1 = *(const short8*)&woT_hi[col * KD + 32 + g * 8];
            const short8 bl0 = *(const short8*)&woT_lo[col * KD + g * 8];
            const short8 bl1 = *(const short8*)&woT_lo[col * KD + 32 + g * 8];
            f32x4 acc = MFMA16(ah0, bh0, zero4);
            acc = MFMA16(ah1, bh1, acc);
            acc = MFMA16(ah0, bl0, acc);
            acc = MFMA16(ah1, bl1, acc);
            acc = MFMA16(al0, bh0, acc);
            acc = MFMA16(al1, bh1, acc);
            const float bias = bo[col];
#pragma unroll
            for (int reg = 0; reg < 4; ++reg)
                out[(size_t)(R0 + 4 * g + reg) * ODIM + col] = acc[reg] + bias;
        }
    }
}

extern "C" void kernel_launch(void* const* d_in, const int* in_sizes, int n_in,
                              void* d_out, int out_size, void* d_ws, size_t ws_size,
                              hipStream_t stream) {
    const float* x     = (const float*)d_in[0];
    const float* w_qkv = (const float*)d_in[1];
    const float* b_qkv = (const float*)d_in[2];
    const float* w_out = (const float*)d_in[3];
    const float* b_out = (const float*)d_in[4];
    const int* causal  = (const int*)d_in[5];
    float* out         = (float*)d_out;

    char* ws = (char*)d_ws;
    ushort_t* wT_hi  = (ushort_t*)(ws);                    // 384 KB
    ushort_t* wT_lo  = (ushort_t*)(ws + 393216);           // 384 KB
    ushort_t* woT_hi = (ushort_t*)(ws + 786432);           // 128 KB
    ushort_t* woT_lo = (ushort_t*)(ws + 917504);           // 128 KB -> 1 MB
    ushort_t* q_hi   = (ushort_t*)(ws + (1u << 20));
    ushort_t* q_lo   = (ushort_t*)(ws + (2u << 20));
    ushort_t* k_hi   = (ushort_t*)(ws + (3u << 20));
    ushort_t* k_lo   = (ushort_t*)(ws + (4u << 20));
    ushort_t* vT     = (ushort_t*)(ws + (5u << 20));       // -> 6 MB
    // x_hi/x_lo [6MB..38MB) are consumed by qkv BEFORE attn writes
    // Opart [6MB..14MB) / MLpart [14MB..14.25MB) -> temporal overlap is safe
    // (single stream, in-order). Peak workspace = 38 MB.
    ushort_t* x_hi   = (ushort_t*)(ws + (6u << 20));       // 16 MB
    ushort_t* x_lo   = (ushort_t*)(ws + (22u << 20));      // 16 MB -> 38 MB
    float*    Opart  = (float*)(ws + (6u << 20));          // 8 MB (after qkv)
    float*    MLpart = (float*)(ws + (14u << 20));         // 256 KB (after qkv)

    prep_kernel<<<5120, 256, 0, stream>>>(w_qkv, w_out, x, wT_hi, wT_lo,
                                          woT_hi, woT_lo, x_hi, x_lo);
    qkv_kernel<<<768, 256, 0, stream>>>(x_hi, x_lo, wT_hi, wT_lo, b_qkv,
                                        q_hi, q_lo, k_hi, k_lo, vT);
    attn_kernel<<<512, 256, 0, stream>>>(q_hi, q_lo, k_hi, k_lo, vT, Opart, MLpart, causal);
    proj_kernel<<<2048, 256, 0, stream>>>(Opart, MLpart, woT_hi, woT_lo, b_out, out);
}